// Round 19
// baseline (540.333 us; speedup 1.0000x reference)
//
#include <hip/hip_runtime.h>

#define S_DIM 1024
#define T_DIM 64
#define B_DIM 8
#define K_DIM 512   // KEY_DIM == QUERY_DIM
#define H_DIM 256
#define NBLK 512

typedef _Float16 f16;
typedef __attribute__((ext_vector_type(4))) _Float16 f16x4;
typedef __attribute__((ext_vector_type(8))) _Float16 f16x8;
typedef __attribute__((ext_vector_type(4))) float f32x4;

__device__ __forceinline__ float fast_rcp(float x) { return __builtin_amdgcn_rcpf(x); }

__device__ __forceinline__ void gload16(const void* g, void* l) {
    __builtin_amdgcn_global_load_lds(
        (const __attribute__((address_space(1))) unsigned int*)g,
        (__attribute__((address_space(3))) unsigned int*)l, 16, 0, 0);
}

// Grid barrier: all-threads-drain + device-scope release/acquire (validated in R8).
__device__ __forceinline__ void gridbar(unsigned* c) {
    __syncthreads();
    __threadfence();
    if (threadIdx.x == 0)
        __hip_atomic_fetch_add(c, 1u, __ATOMIC_ACQ_REL, __HIP_MEMORY_SCOPE_AGENT);
    while (__hip_atomic_load(c, __ATOMIC_ACQUIRE, __HIP_MEMORY_SCOPE_AGENT) < (unsigned)NBLK)
        __builtin_amdgcn_s_sleep(2);
    __syncthreads();
}

// Persistent mega-kernel. 512 blocks, 32KB LDS, VGPR<=256 (launch_bounds) ->
// co-residency capacity >= 768 blocks: all 512 resident, barriers safe.
// W: Wk/Wq -> f16 WT[H][K] (blocks 0-63).
// P: E=exp(2(A@W+b)); 1088 tiles (32mx64n), key->ktT4[b][h/4][s][4], query->tq2[b][t][h].
// S: scores = -2*sum v/(Eq*Ek+1)  (1024 units, R17 structure).
// M: softmax (512 rows).
__global__ __launch_bounds__(256, 2) void mega_kernel(
    const float* __restrict__ key, const float* __restrict__ query,
    const float* __restrict__ Wk, const float* __restrict__ bk,
    const float* __restrict__ Wq, const float* __restrict__ bq,
    const float* __restrict__ v,
    f16* __restrict__ WTk, f16* __restrict__ WTq,
    float* __restrict__ ktT, float* __restrict__ tq2,
    float* __restrict__ scores, float* __restrict__ out, unsigned* cnt)
{
    __shared__ __align__(16) char smem[32768];
    const int tid = threadIdx.x;
    const int lane = tid & 63, wid = tid >> 6;
    const int widu = __builtin_amdgcn_readfirstlane(wid);
    const int bid = blockIdx.x;

    // ================= Phase W: W transpose+convert =================
    if (bid < 64) {
        float (*wt)[65] = (float(*)[65])smem;   // 16.6 KB
        const float* W = (bid & 32) ? Wq : Wk;
        f16* WT = (bid & 32) ? WTq : WTk;
        const int t32 = bid & 31;
        const int k0 = (t32 >> 2) * 64, n0 = (t32 & 3) * 64;
        const int c = tid & 63, r0 = tid >> 6;
#pragma unroll
        for (int i = 0; i < 16; ++i) {
            int r = r0 + i * 4;
            wt[r][c] = W[(size_t)(k0 + r) * H_DIM + n0 + c];
        }
        __syncthreads();
#pragma unroll
        for (int i = 0; i < 16; ++i) {
            int r = r0 + i * 4;
            WT[(size_t)(n0 + r) * K_DIM + k0 + c] = (f16)wt[c][r];
        }
    }
    gridbar(&cnt[0]);

    // ================= Phase P: projections =================
    {
        const int wm = (wid >> 1) * 16, wn = (wid & 1) * 32;
        const int fr = lane & 15, fgb = (lane >> 4) << 4;
        const int crow = (lane >> 4) * 4, ccol = lane & 15;
        char* SB0 = smem;            // buf0
        char* SB1 = smem + 16384;    // buf1

        auto do_proj = [&](int rawtile) {
            const int t8 = (rawtile & 7) * 136 + (rawtile >> 3);   // bijective 1088 = 8*136
            const bool isQ = t8 >= 1024;
            const int lb = isQ ? t8 - 1024 : t8;
            const size_t m0 = (size_t)(lb >> 2) * 32;
            const int n0 = (lb & 3) * 64;
            const float* A    = isQ ? query : key;
            const f16* BT     = isQ ? WTq : WTk;
            const float* bias = isQ ? bq : bk;

            const int o0 = tid << 4;
            const int o1 = o0 + 4096;
            const int row0 = o0 >> 7, kb0 = (o0 & 127) ^ ((row0 & 7) << 4);
            const int row1 = o1 >> 7, kb1 = (o1 & 127) ^ ((row1 & 7) << 4);
            const char* b_t = (const char*)(BT + (size_t)n0 * K_DIM);

            auto GLOADB = [&](char* SB, int t) {
                const int kb = t * 128;
                char* d0 = SB + 8192 + widu * 1024;
                gload16(b_t + (size_t)row0 * 1024 + kb + kb0, d0);
                gload16(b_t + (size_t)row1 * 1024 + kb + kb1, d0 + 4096);
            };

            const float* a_base = A + m0 * K_DIM;
            float4 areg[2];
            auto ALOAD = [&](int t) {
#pragma unroll
                for (int j = 0; j < 2; ++j) {
                    const int fidx = j * 256 + tid;
                    const int r = fidx >> 4, c16 = fidx & 15;
                    areg[j] = *(const float4*)&a_base[(size_t)r * K_DIM + t * 64 + c16 * 4];
                }
            };
            auto AWRITE = [&](char* SB) {
#pragma unroll
                for (int j = 0; j < 2; ++j) {
                    const int fidx = j * 256 + tid;
                    const int r = fidx >> 4, c16 = fidx & 15;
                    const int byt = r * 128 + ((c16 * 8) ^ ((r & 7) << 4));
                    f16 h0 = (f16)areg[j].x, h1 = (f16)areg[j].y, h2 = (f16)areg[j].z, h3 = (f16)areg[j].w;
                    f16x4 hi = {h0, h1, h2, h3};
                    f16x4 lo = {(f16)(areg[j].x - (float)h0), (f16)(areg[j].y - (float)h1),
                                (f16)(areg[j].z - (float)h2), (f16)(areg[j].w - (float)h3)};
                    *(f16x4*)&SB[byt] = hi;
                    *(f16x4*)&SB[4096 + byt] = lo;
                }
            };

            f32x4 acc[2] = {};
            auto COMPUTE = [&](char* SB) {
#pragma unroll
                for (int kk = 0; kk < 2; ++kk) {
                    const int kbyte = kk * 64 + fgb;
                    const int arow = wm + fr;
                    const int abyt = (arow << 7) + (kbyte ^ ((arow & 7) << 4));
                    f16x8 ah = *(const f16x8*)&SB[abyt];
                    f16x8 al = *(const f16x8*)&SB[4096 + abyt];
                    const int brow0 = wn + fr, brow1 = wn + 16 + fr;
                    f16x8 b0 = *(const f16x8*)&SB[8192 + (brow0 << 7) + (kbyte ^ ((brow0 & 7) << 4))];
                    f16x8 b1 = *(const f16x8*)&SB[8192 + (brow1 << 7) + (kbyte ^ ((brow1 & 7) << 4))];
                    acc[0] = __builtin_amdgcn_mfma_f32_16x16x32_f16(ah, b0, acc[0], 0, 0, 0);
                    acc[1] = __builtin_amdgcn_mfma_f32_16x16x32_f16(ah, b1, acc[1], 0, 0, 0);
                    acc[0] = __builtin_amdgcn_mfma_f32_16x16x32_f16(al, b0, acc[0], 0, 0, 0);
                    acc[1] = __builtin_amdgcn_mfma_f32_16x16x32_f16(al, b1, acc[1], 0, 0, 0);
                }
            };

            __syncthreads();               // protect smem reuse from previous tile
            ALOAD(0);
            GLOADB(SB0, 0);
            AWRITE(SB0);
            __syncthreads();

            char* bufs[2] = {SB0, SB1};
            int buf = 0;
#pragma unroll 1
            for (int t = 0; t < 8; ++t) {
                if (t < 7) { ALOAD(t + 1); GLOADB(bufs[buf ^ 1], t + 1); }
                COMPUTE(bufs[buf]);
                if (t < 7) { AWRITE(bufs[buf ^ 1]); __syncthreads(); }
                buf ^= 1;
            }

            if (isQ) {
#pragma unroll
                for (int g = 0; g < 2; ++g) {
                    int col = n0 + wn + g * 16 + ccol;
                    float bv = bias[col];
#pragma unroll
                    for (int r = 0; r < 4; ++r) {
                        size_t row = m0 + wm + crow + r;
                        float val = __expf(2.0f * (acc[g][r] + bv));
                        tq2[((size_t)(row & 7) * T_DIM + (row >> 3)) * H_DIM + col] = val;
                    }
                }
            } else {
                float* lt = (float*)SB0;   // 8KB stage [32 lrow][64 lcol]; lrow = s_off*8+b
#pragma unroll
                for (int g = 0; g < 2; ++g) {
                    int lcol = wn + g * 16 + ccol;
                    float bv = bias[n0 + lcol];
#pragma unroll
                    for (int r = 0; r < 4; ++r) {
                        int lrow = wm + crow + r;
                        lt[lrow * 64 + lcol] = __expf(2.0f * (acc[g][r] + bv));
                    }
                }
                __syncthreads();
                // h-quad gather -> ktT4[b][h/4][s][4], 64B-contiguous store groups
                const int sbase = (int)(m0 >> 3);
                const int n0q = n0 >> 2;
#pragma unroll
                for (int p = 0; p < 2; ++p) {
                    int c = p * 256 + tid;
                    int s_off = c & 3, h4 = (c >> 2) & 15, b2 = c >> 6;
                    float4 o = *(const float4*)&lt[(s_off * 8 + b2) * 64 + h4 * 4];
                    size_t f4idx = ((size_t)b2 * 64 + n0q + h4) * S_DIM + sbase + s_off;
                    *(float4*)&ktT[f4idx * 4] = o;
                }
            }
        };

#pragma unroll 1
        for (int w = 0; w < 3; ++w) {
            int tile = bid + w * NBLK;
            if (tile < 1088) do_proj(tile);
        }
    }
    gridbar(&cnt[1]);

    // ================= Phase S: scores (R17 structure, 2 units/block) =================
    {
        auto do_scores = [&](int bb) {
            const int b = bb & 7;
            const int sblk = (bb >> 3) & 15;
            const int t0 = ((bb >> 7) << 3) + wid * 2;
            const int s = sblk * 64 + lane;

            const float4* kb4 = (const float4*)ktT + (size_t)b * 64 * S_DIM + s;
            const float* q0p = tq2 + ((size_t)b * T_DIM + t0) * H_DIM;
            const float* q1p = q0p + H_DIM;
            float* so = scores + ((size_t)b * T_DIM + t0) * S_DIM + s;

            float a0 = 0.f, a1 = 0.f;
#pragma unroll 8
            for (int h4 = 0; h4 < H_DIM / 4; ++h4) {
                float4 k4 = kb4[(size_t)h4 * S_DIM];
                float4 vv = *(const float4*)&v[h4 * 4];
                float4 q0 = *(const float4*)&q0p[h4 * 4];
                float4 q1 = *(const float4*)&q1p[h4 * 4];
                float A, B;
                A = fmaf(q0.x, k4.x, 1.0f); B = fmaf(q0.y, k4.y, 1.0f);
                a0 = fmaf(fmaf(vv.x, B, vv.y * A), fast_rcp(A * B), a0);
                A = fmaf(q0.z, k4.z, 1.0f); B = fmaf(q0.w, k4.w, 1.0f);
                a0 = fmaf(fmaf(vv.z, B, vv.w * A), fast_rcp(A * B), a0);
                A = fmaf(q1.x, k4.x, 1.0f); B = fmaf(q1.y, k4.y, 1.0f);
                a1 = fmaf(fmaf(vv.x, B, vv.y * A), fast_rcp(A * B), a1);
                A = fmaf(q1.z, k4.z, 1.0f); B = fmaf(q1.w, k4.w, 1.0f);
                a1 = fmaf(fmaf(vv.z, B, vv.w * A), fast_rcp(A * B), a1);
            }
            so[0]     = -2.0f * a0;
            so[S_DIM] = -2.0f * a1;
        };
        do_scores(bid);
        do_scores(bid + NBLK);
    }
    gridbar(&cnt[2]);

    // ================= Phase M: softmax (1 row/block) =================
    {
        float* red = (float*)smem;
        const int row = bid;             // b*T + t, 512 rows
        float4 x = ((const float4*)(scores + (size_t)row * S_DIM))[tid];
        float m = fmaxf(fmaxf(x.x, x.y), fmaxf(x.z, x.w));
#pragma unroll
        for (int mm = 32; mm >= 1; mm >>= 1) m = fmaxf(m, __shfl_xor(m, mm, 64));
        if (lane == 0) red[wid] = m;
        __syncthreads();
        m = fmaxf(fmaxf(red[0], red[1]), fmaxf(red[2], red[3]));
        float e0 = __expf(x.x - m), e1 = __expf(x.y - m);
        float e2 = __expf(x.z - m), e3 = __expf(x.w - m);
        float sum = e0 + e1 + e2 + e3;
#pragma unroll
        for (int mm = 32; mm >= 1; mm >>= 1) sum += __shfl_xor(sum, mm, 64);
        if (lane == 0) red[4 + wid] = sum;
        __syncthreads();
        float inv = fast_rcp(red[4] + red[5] + red[6] + red[7]);
        float4 o;
        o.x = e0 * inv; o.y = e1 * inv; o.z = e2 * inv; o.w = e3 * inv;
        ((float4*)(out + (size_t)row * S_DIM))[tid] = o;
    }
}

extern "C" void kernel_launch(void* const* d_in, const int* in_sizes, int n_in,
                              void* d_out, int out_size, void* d_ws, size_t ws_size,
                              hipStream_t stream)
{
    const float* key   = (const float*)d_in[0];
    const float* query = (const float*)d_in[1];
    const float* Wk    = (const float*)d_in[2];
    const float* bk    = (const float*)d_in[3];
    const float* Wq    = (const float*)d_in[4];
    const float* bq    = (const float*)d_in[5];
    const float* v     = (const float*)d_in[6];
    float* out = (float*)d_out;

    float* ktT    = (float*)d_ws;                       // B*(H/4)*S*4 f32 (8.39 MB)
    float* tq2    = ktT + (size_t)B_DIM * H_DIM * S_DIM;// B*T*H f32  (0.52 MB)
    float* scores = tq2 + (size_t)B_DIM * T_DIM * H_DIM;// B*T*S f32  (2.10 MB)
    f16* WTk = (f16*)(scores + (size_t)B_DIM * T_DIM * S_DIM);  // H*K f16
    f16* WTq = WTk + (size_t)H_DIM * K_DIM;                     // H*K f16
    unsigned* cnt = (unsigned*)(WTq + (size_t)H_DIM * K_DIM);   // 3 barrier counters

    hipMemsetAsync(cnt, 0, 3 * sizeof(unsigned), stream);
    mega_kernel<<<NBLK, 256, 0, stream>>>(key, query, Wk, bk, Wq, bq, v,
                                          WTk, WTq, ktT, tq2, scores, out, cnt);
}

// Round 20
// 324.756 us; speedup vs baseline: 1.6638x; 1.6638x over previous
//
#include <hip/hip_runtime.h>

#define S_DIM 1024
#define T_DIM 64
#define B_DIM 8
#define K_DIM 512   // KEY_DIM == QUERY_DIM
#define H_DIM 256
#define NBLK 512

typedef _Float16 f16;
typedef __attribute__((ext_vector_type(4))) _Float16 f16x4;
typedef __attribute__((ext_vector_type(8))) _Float16 f16x8;
typedef __attribute__((ext_vector_type(4))) float f32x4;

__device__ __forceinline__ float fast_rcp(float x) { return __builtin_amdgcn_rcpf(x); }

__device__ __forceinline__ void gload16(const void* g, void* l) {
    __builtin_amdgcn_global_load_lds(
        (const __attribute__((address_space(1))) unsigned int*)g,
        (__attribute__((address_space(3))) unsigned int*)l, 16, 0, 0);
}

// Grid barrier, contention-fixed: ONLY thread 0 spins (512 spinners, not 131K).
// Thread-0's agent-scope acquire load invalidates the CU's L1 before the
// closing __syncthreads, so all block threads see remote released writes.
__device__ __forceinline__ void gridbar(unsigned* c) {
    __syncthreads();
    __threadfence();                               // release: make our writes visible
    if (threadIdx.x == 0) {
        __hip_atomic_fetch_add(c, 1u, __ATOMIC_ACQ_REL, __HIP_MEMORY_SCOPE_AGENT);
        while (__hip_atomic_load(c, __ATOMIC_ACQUIRE, __HIP_MEMORY_SCOPE_AGENT) < (unsigned)NBLK)
            __builtin_amdgcn_s_sleep(8);
    }
    __syncthreads();
}

// Persistent mega-kernel. 512 blocks, 32KB LDS, VGPR=64 -> all 512 co-resident
// (2 blocks/CU, verified by R19's 24.4% occupancy).
// W: Wk/Wq -> f16 WT[H][K] (blocks 0-63).
// P: E=exp(2(A@W+b)); 1088 tiles (32mx64n), key->ktT4[b][h/4][s][4], query->tq2[b][t][h].
// S: scores = -2*sum v/(Eq*Ek+1)  (1024 units, R17 structure).
// M: softmax (512 rows).
__global__ __launch_bounds__(256, 2) void mega_kernel(
    const float* __restrict__ key, const float* __restrict__ query,
    const float* __restrict__ Wk, const float* __restrict__ bk,
    const float* __restrict__ Wq, const float* __restrict__ bq,
    const float* __restrict__ v,
    f16* __restrict__ WTk, f16* __restrict__ WTq,
    float* __restrict__ ktT, float* __restrict__ tq2,
    float* __restrict__ scores, float* __restrict__ out, unsigned* cnt)
{
    __shared__ __align__(16) char smem[32768];
    const int tid = threadIdx.x;
    const int lane = tid & 63, wid = tid >> 6;
    const int widu = __builtin_amdgcn_readfirstlane(wid);
    const int bid = blockIdx.x;

    // ================= Phase W: W transpose+convert =================
    if (bid < 64) {
        float (*wt)[65] = (float(*)[65])smem;   // 16.6 KB
        const float* W = (bid & 32) ? Wq : Wk;
        f16* WT = (bid & 32) ? WTq : WTk;
        const int t32 = bid & 31;
        const int k0 = (t32 >> 2) * 64, n0 = (t32 & 3) * 64;
        const int c = tid & 63, r0 = tid >> 6;
#pragma unroll
        for (int i = 0; i < 16; ++i) {
            int r = r0 + i * 4;
            wt[r][c] = W[(size_t)(k0 + r) * H_DIM + n0 + c];
        }
        __syncthreads();
#pragma unroll
        for (int i = 0; i < 16; ++i) {
            int r = r0 + i * 4;
            WT[(size_t)(n0 + r) * K_DIM + k0 + c] = (f16)wt[c][r];
        }
    }
    gridbar(&cnt[0]);

    // ================= Phase P: projections =================
    {
        const int wm = (wid >> 1) * 16, wn = (wid & 1) * 32;
        const int fr = lane & 15, fgb = (lane >> 4) << 4;
        const int crow = (lane >> 4) * 4, ccol = lane & 15;
        char* SB0 = smem;            // buf0
        char* SB1 = smem + 16384;    // buf1

        auto do_proj = [&](int rawtile) {
            const int t8 = (rawtile & 7) * 136 + (rawtile >> 3);   // bijective 1088 = 8*136
            const bool isQ = t8 >= 1024;
            const int lb = isQ ? t8 - 1024 : t8;
            const size_t m0 = (size_t)(lb >> 2) * 32;
            const int n0 = (lb & 3) * 64;
            const float* A    = isQ ? query : key;
            const f16* BT     = isQ ? WTq : WTk;
            const float* bias = isQ ? bq : bk;

            const int o0 = tid << 4;
            const int o1 = o0 + 4096;
            const int row0 = o0 >> 7, kb0 = (o0 & 127) ^ ((row0 & 7) << 4);
            const int row1 = o1 >> 7, kb1 = (o1 & 127) ^ ((row1 & 7) << 4);
            const char* b_t = (const char*)(BT + (size_t)n0 * K_DIM);

            auto GLOADB = [&](char* SB, int t) {
                const int kb = t * 128;
                char* d0 = SB + 8192 + widu * 1024;
                gload16(b_t + (size_t)row0 * 1024 + kb + kb0, d0);
                gload16(b_t + (size_t)row1 * 1024 + kb + kb1, d0 + 4096);
            };

            const float* a_base = A + m0 * K_DIM;
            float4 areg[2];
            auto ALOAD = [&](int t) {
#pragma unroll
                for (int j = 0; j < 2; ++j) {
                    const int fidx = j * 256 + tid;
                    const int r = fidx >> 4, c16 = fidx & 15;
                    areg[j] = *(const float4*)&a_base[(size_t)r * K_DIM + t * 64 + c16 * 4];
                }
            };
            auto AWRITE = [&](char* SB) {
#pragma unroll
                for (int j = 0; j < 2; ++j) {
                    const int fidx = j * 256 + tid;
                    const int r = fidx >> 4, c16 = fidx & 15;
                    const int byt = r * 128 + ((c16 * 8) ^ ((r & 7) << 4));
                    f16 h0 = (f16)areg[j].x, h1 = (f16)areg[j].y, h2 = (f16)areg[j].z, h3 = (f16)areg[j].w;
                    f16x4 hi = {h0, h1, h2, h3};
                    f16x4 lo = {(f16)(areg[j].x - (float)h0), (f16)(areg[j].y - (float)h1),
                                (f16)(areg[j].z - (float)h2), (f16)(areg[j].w - (float)h3)};
                    *(f16x4*)&SB[byt] = hi;
                    *(f16x4*)&SB[4096 + byt] = lo;
                }
            };

            f32x4 acc[2] = {};
            auto COMPUTE = [&](char* SB) {
#pragma unroll
                for (int kk = 0; kk < 2; ++kk) {
                    const int kbyte = kk * 64 + fgb;
                    const int arow = wm + fr;
                    const int abyt = (arow << 7) + (kbyte ^ ((arow & 7) << 4));
                    f16x8 ah = *(const f16x8*)&SB[abyt];
                    f16x8 al = *(const f16x8*)&SB[4096 + abyt];
                    const int brow0 = wn + fr, brow1 = wn + 16 + fr;
                    f16x8 b0 = *(const f16x8*)&SB[8192 + (brow0 << 7) + (kbyte ^ ((brow0 & 7) << 4))];
                    f16x8 b1 = *(const f16x8*)&SB[8192 + (brow1 << 7) + (kbyte ^ ((brow1 & 7) << 4))];
                    acc[0] = __builtin_amdgcn_mfma_f32_16x16x32_f16(ah, b0, acc[0], 0, 0, 0);
                    acc[1] = __builtin_amdgcn_mfma_f32_16x16x32_f16(ah, b1, acc[1], 0, 0, 0);
                    acc[0] = __builtin_amdgcn_mfma_f32_16x16x32_f16(al, b0, acc[0], 0, 0, 0);
                    acc[1] = __builtin_amdgcn_mfma_f32_16x16x32_f16(al, b1, acc[1], 0, 0, 0);
                }
            };

            __syncthreads();               // protect smem reuse from previous tile
            ALOAD(0);
            GLOADB(SB0, 0);
            AWRITE(SB0);
            __syncthreads();

            char* bufs[2] = {SB0, SB1};
            int buf = 0;
#pragma unroll 1
            for (int t = 0; t < 8; ++t) {
                if (t < 7) { ALOAD(t + 1); GLOADB(bufs[buf ^ 1], t + 1); }
                COMPUTE(bufs[buf]);
                if (t < 7) { AWRITE(bufs[buf ^ 1]); __syncthreads(); }
                buf ^= 1;
            }

            if (isQ) {
#pragma unroll
                for (int g = 0; g < 2; ++g) {
                    int col = n0 + wn + g * 16 + ccol;
                    float bv = bias[col];
#pragma unroll
                    for (int r = 0; r < 4; ++r) {
                        size_t row = m0 + wm + crow + r;
                        float val = __expf(2.0f * (acc[g][r] + bv));
                        tq2[((size_t)(row & 7) * T_DIM + (row >> 3)) * H_DIM + col] = val;
                    }
                }
            } else {
                float* lt = (float*)SB0;   // 8KB stage [32 lrow][64 lcol]; lrow = s_off*8+b
#pragma unroll
                for (int g = 0; g < 2; ++g) {
                    int lcol = wn + g * 16 + ccol;
                    float bv = bias[n0 + lcol];
#pragma unroll
                    for (int r = 0; r < 4; ++r) {
                        int lrow = wm + crow + r;
                        lt[lrow * 64 + lcol] = __expf(2.0f * (acc[g][r] + bv));
                    }
                }
                __syncthreads();
                // h-quad gather -> ktT4[b][h/4][s][4], 64B-contiguous store groups
                const int sbase = (int)(m0 >> 3);
                const int n0q = n0 >> 2;
#pragma unroll
                for (int p = 0; p < 2; ++p) {
                    int c = p * 256 + tid;
                    int s_off = c & 3, h4 = (c >> 2) & 15, b2 = c >> 6;
                    float4 o = *(const float4*)&lt[(s_off * 8 + b2) * 64 + h4 * 4];
                    size_t f4idx = ((size_t)b2 * 64 + n0q + h4) * S_DIM + sbase + s_off;
                    *(float4*)&ktT[f4idx * 4] = o;
                }
            }
        };

#pragma unroll 1
        for (int w = 0; w < 3; ++w) {
            int tile = bid + w * NBLK;
            if (tile < 1088) do_proj(tile);
        }
    }
    gridbar(&cnt[1]);

    // ================= Phase S: scores (R17 structure, 2 units/block) =================
    {
        auto do_scores = [&](int bb) {
            const int b = bb & 7;
            const int sblk = (bb >> 3) & 15;
            const int t0 = ((bb >> 7) << 3) + wid * 2;
            const int s = sblk * 64 + lane;

            const float4* kb4 = (const float4*)ktT + (size_t)b * 64 * S_DIM + s;
            const float* q0p = tq2 + ((size_t)b * T_DIM + t0) * H_DIM;
            const float* q1p = q0p + H_DIM;
            float* so = scores + ((size_t)b * T_DIM + t0) * S_DIM + s;

            float a0 = 0.f, a1 = 0.f;
#pragma unroll 8
            for (int h4 = 0; h4 < H_DIM / 4; ++h4) {
                float4 k4 = kb4[(size_t)h4 * S_DIM];
                float4 vv = *(const float4*)&v[h4 * 4];
                float4 q0 = *(const float4*)&q0p[h4 * 4];
                float4 q1 = *(const float4*)&q1p[h4 * 4];
                float A, B;
                A = fmaf(q0.x, k4.x, 1.0f); B = fmaf(q0.y, k4.y, 1.0f);
                a0 = fmaf(fmaf(vv.x, B, vv.y * A), fast_rcp(A * B), a0);
                A = fmaf(q0.z, k4.z, 1.0f); B = fmaf(q0.w, k4.w, 1.0f);
                a0 = fmaf(fmaf(vv.z, B, vv.w * A), fast_rcp(A * B), a0);
                A = fmaf(q1.x, k4.x, 1.0f); B = fmaf(q1.y, k4.y, 1.0f);
                a1 = fmaf(fmaf(vv.x, B, vv.y * A), fast_rcp(A * B), a1);
                A = fmaf(q1.z, k4.z, 1.0f); B = fmaf(q1.w, k4.w, 1.0f);
                a1 = fmaf(fmaf(vv.z, B, vv.w * A), fast_rcp(A * B), a1);
            }
            so[0]     = -2.0f * a0;
            so[S_DIM] = -2.0f * a1;
        };
        do_scores(bid);
        do_scores(bid + NBLK);
    }
    gridbar(&cnt[2]);

    // ================= Phase M: softmax (1 row/block) =================
    {
        float* red = (float*)smem;
        const int row = bid;             // b*T + t, 512 rows
        float4 x = ((const float4*)(scores + (size_t)row * S_DIM))[tid];
        float m = fmaxf(fmaxf(x.x, x.y), fmaxf(x.z, x.w));
#pragma unroll
        for (int mm = 32; mm >= 1; mm >>= 1) m = fmaxf(m, __shfl_xor(m, mm, 64));
        if (lane == 0) red[wid] = m;
        __syncthreads();
        m = fmaxf(fmaxf(red[0], red[1]), fmaxf(red[2], red[3]));
        float e0 = __expf(x.x - m), e1 = __expf(x.y - m);
        float e2 = __expf(x.z - m), e3 = __expf(x.w - m);
        float sum = e0 + e1 + e2 + e3;
#pragma unroll
        for (int mm = 32; mm >= 1; mm >>= 1) sum += __shfl_xor(sum, mm, 64);
        if (lane == 0) red[4 + wid] = sum;
        __syncthreads();
        float inv = fast_rcp(red[4] + red[5] + red[6] + red[7]);
        float4 o;
        o.x = e0 * inv; o.y = e1 * inv; o.z = e2 * inv; o.w = e3 * inv;
        ((float4*)(out + (size_t)row * S_DIM))[tid] = o;
    }
}

extern "C" void kernel_launch(void* const* d_in, const int* in_sizes, int n_in,
                              void* d_out, int out_size, void* d_ws, size_t ws_size,
                              hipStream_t stream)
{
    const float* key   = (const float*)d_in[0];
    const float* query = (const float*)d_in[1];
    const float* Wk    = (const float*)d_in[2];
    const float* bk    = (const float*)d_in[3];
    const float* Wq    = (const float*)d_in[4];
    const float* bq    = (const float*)d_in[5];
    const float* v     = (const float*)d_in[6];
    float* out = (float*)d_out;

    float* ktT    = (float*)d_ws;                       // B*(H/4)*S*4 f32 (8.39 MB)
    float* tq2    = ktT + (size_t)B_DIM * H_DIM * S_DIM;// B*T*H f32  (0.52 MB)
    float* scores = tq2 + (size_t)B_DIM * T_DIM * H_DIM;// B*T*S f32  (2.10 MB)
    f16* WTk = (f16*)(scores + (size_t)B_DIM * T_DIM * S_DIM);  // H*K f16
    f16* WTq = WTk + (size_t)H_DIM * K_DIM;                     // H*K f16
    unsigned* cnt = (unsigned*)(WTq + (size_t)H_DIM * K_DIM);   // 3 barrier counters

    hipMemsetAsync(cnt, 0, 3 * sizeof(unsigned), stream);
    mega_kernel<<<NBLK, 256, 0, stream>>>(key, query, Wk, bk, Wq, bq, v,
                                          WTk, WTq, ktT, tq2, scores, out, cnt);
}

// Round 21
// 44.235 us; speedup vs baseline: 12.2151x; 7.3416x over previous
//
#include <hip/hip_runtime.h>

#define S_DIM 1024
#define T_DIM 64
#define B_DIM 8
#define K_DIM 512   // KEY_DIM == QUERY_DIM
#define H_DIM 256

typedef _Float16 f16;
typedef __attribute__((ext_vector_type(4))) _Float16 f16x4;
typedef __attribute__((ext_vector_type(8))) _Float16 f16x8;
typedef __attribute__((ext_vector_type(4))) float f32x4;

__device__ __forceinline__ float fast_rcp(float x) { return __builtin_amdgcn_rcpf(x); }

__device__ __forceinline__ void gload16(const void* g, void* l) {
    __builtin_amdgcn_global_load_lds(
        (const __attribute__((address_space(1))) unsigned int*)g,
        (__attribute__((address_space(3))) unsigned int*)l, 16, 0, 0);
}

// W transpose+convert only: Wk/Wq [K][H] f32 -> WT [H][K] f16  (1 MB total)
__global__ __launch_bounds__(256) void wconv_kernel(
    const float* __restrict__ Wk, const float* __restrict__ Wq,
    f16* __restrict__ WTk, f16* __restrict__ WTq)
{
    __shared__ float tile[64][65];
    const int idx = blockIdx.x;            // 64 blocks: 2 mats x 32 tiles
    const float* W = (idx & 32) ? Wq : Wk;
    f16* WT = (idx & 32) ? WTq : WTk;
    const int t32 = idx & 31;
    const int k0 = (t32 >> 2) * 64, n0 = (t32 & 3) * 64;
    const int c = threadIdx.x & 63, r0 = threadIdx.x >> 6;
#pragma unroll
    for (int i = 0; i < 16; ++i) {
        int r = r0 + i * 4;
        tile[r][c] = W[(size_t)(k0 + r) * H_DIM + n0 + c];
    }
    __syncthreads();
#pragma unroll
    for (int i = 0; i < 16; ++i) {
        int r = r0 + i * 4;
        WT[(size_t)(n0 + r) * K_DIM + k0 + c] = (f16)tile[c][r];
    }
}

// E = exp(2*(A @ W + bias)); 32m x 64n tile, 4 waves of 16m x 32n; grid 1088.
// key half : epilogue LDS-transpose -> ktT4[b][h/4][s][4]  (h-quad interleaved).
// query half: direct tq2[b][t][h] writes.   (R17-identical)
__global__ __launch_bounds__(256, 4) void proj_gemm_all(
    const float* __restrict__ key, const f16* __restrict__ WTk,
    const float* __restrict__ bk, float* __restrict__ ktT,
    const float* __restrict__ query, const f16* __restrict__ WTq,
    const float* __restrict__ bq, float* __restrict__ tq2)
{
    // [buf][ Ahi 4KB | Alo 4KB | B 8KB ]
    __shared__ __align__(16) char smem[2][16384];
    const int tid = threadIdx.x;
    const int lane = tid & 63, wid = tid >> 6;
    const int widu = __builtin_amdgcn_readfirstlane(wid);
    const int wm = (wid >> 1) * 16, wn = (wid & 1) * 32;

    // bijective XCD swizzle: 1088 = 8*136
    const int bid0 = blockIdx.x;
    const int bid = (bid0 & 7) * 136 + (bid0 >> 3);
    const bool isQ = bid >= 1024;
    const int lb = isQ ? bid - 1024 : bid;
    const size_t m0 = (size_t)(lb >> 2) * 32;
    const int n0 = (lb & 3) * 64;
    const float* A    = isQ ? query : key;
    const f16* BT     = isQ ? WTq : WTk;
    const float* bias = isQ ? bq : bk;

    // ---- B staging via global_load_lds (swizzled source, linear dest) ----
    const int o0 = tid << 4;               // [0,4096): rows 0..31
    const int o1 = o0 + 4096;              // rows 32..63
    const int row0 = o0 >> 7, kb0 = (o0 & 127) ^ ((row0 & 7) << 4);
    const int row1 = o1 >> 7, kb1 = (o1 & 127) ^ ((row1 & 7) << 4);
    const char* b_t = (const char*)(BT + (size_t)n0 * K_DIM);   // row stride 1024 B

    auto GLOADB = [&](int buf, int t) {
        const int kb = t * 128;
        char* d0 = &smem[buf][8192 + widu * 1024];
        gload16(b_t + (size_t)row0 * 1024 + kb + kb0, d0);
        gload16(b_t + (size_t)row1 * 1024 + kb + kb1, d0 + 4096);
    };

    // ---- A staging: 32 rows x 64 k f32 = 512 float4; 256 thr x 2 ----
    const float* a_base = A + m0 * K_DIM;
    float4 areg[2];
    auto ALOAD = [&](int t) {
#pragma unroll
        for (int j = 0; j < 2; ++j) {
            const int fidx = j * 256 + tid;
            const int r = fidx >> 4, c16 = fidx & 15;
            areg[j] = *(const float4*)&a_base[(size_t)r * K_DIM + t * 64 + c16 * 4];
        }
    };
    auto AWRITE = [&](int buf) {
#pragma unroll
        for (int j = 0; j < 2; ++j) {
            const int fidx = j * 256 + tid;
            const int r = fidx >> 4, c16 = fidx & 15;
            const int byt = r * 128 + ((c16 * 8) ^ ((r & 7) << 4));
            f16 h0 = (f16)areg[j].x, h1 = (f16)areg[j].y, h2 = (f16)areg[j].z, h3 = (f16)areg[j].w;
            f16x4 hi = {h0, h1, h2, h3};
            f16x4 lo = {(f16)(areg[j].x - (float)h0), (f16)(areg[j].y - (float)h1),
                        (f16)(areg[j].z - (float)h2), (f16)(areg[j].w - (float)h3)};
            *(f16x4*)&smem[buf][byt] = hi;
            *(f16x4*)&smem[buf][4096 + byt] = lo;
        }
    };

    f32x4 acc[2] = {};
    const int fr = lane & 15, fgb = (lane >> 4) << 4;

    auto COMPUTE = [&](int buf) {
#pragma unroll
        for (int kk = 0; kk < 2; ++kk) {
            const int kbyte = kk * 64 + fgb;
            const int arow = wm + fr;
            const int abyt = (arow << 7) + (kbyte ^ ((arow & 7) << 4));
            f16x8 ah = *(const f16x8*)&smem[buf][abyt];
            f16x8 al = *(const f16x8*)&smem[buf][4096 + abyt];
            const int brow0 = wn + fr, brow1 = wn + 16 + fr;
            f16x8 b0 = *(const f16x8*)&smem[buf][8192 + (brow0 << 7) + (kbyte ^ ((brow0 & 7) << 4))];
            f16x8 b1 = *(const f16x8*)&smem[buf][8192 + (brow1 << 7) + (kbyte ^ ((brow1 & 7) << 4))];
            acc[0] = __builtin_amdgcn_mfma_f32_16x16x32_f16(ah, b0, acc[0], 0, 0, 0);
            acc[1] = __builtin_amdgcn_mfma_f32_16x16x32_f16(ah, b1, acc[1], 0, 0, 0);
            acc[0] = __builtin_amdgcn_mfma_f32_16x16x32_f16(al, b0, acc[0], 0, 0, 0);
            acc[1] = __builtin_amdgcn_mfma_f32_16x16x32_f16(al, b1, acc[1], 0, 0, 0);
        }
    };

    // prologue: tile 0
    ALOAD(0);
    GLOADB(0, 0);
    AWRITE(0);
    __syncthreads();

    int buf = 0;
#pragma unroll 1
    for (int t = 0; t < 8; ++t) {
        if (t < 7) {
            ALOAD(t + 1);             // issue next-tile loads BEFORE compute
            GLOADB(buf ^ 1, t + 1);
        }
        COMPUTE(buf);
        if (t < 7) {
            AWRITE(buf ^ 1);
            __syncthreads();          // drains gloadB(buf^1); protects buf reuse
        }
        buf ^= 1;
    }

    // C/D layout (m89): col = lane&15, row = (lane>>4)*4 + reg
    const int crow = (lane >> 4) * 4, ccol = lane & 15;
    if (isQ) {
#pragma unroll
        for (int g = 0; g < 2; ++g) {
            int col = n0 + wn + g * 16 + ccol;
            float bv = bias[col];
#pragma unroll
            for (int r = 0; r < 4; ++r) {
                size_t row = m0 + wm + crow + r;
                float val = __expf(2.0f * (acc[g][r] + bv));
                tq2[((size_t)(row & 7) * T_DIM + (row >> 3)) * H_DIM + col] = val;  // [b][t][h]
            }
        }
    } else {
        // stage exp values into 8KB LDS tile [32 lrow][64 lcol]; lrow = s_off*8 + b
        float* lt = (float*)&smem[0][0];
#pragma unroll
        for (int g = 0; g < 2; ++g) {
            int lcol = wn + g * 16 + ccol;
            float bv = bias[n0 + lcol];
#pragma unroll
            for (int r = 0; r < 4; ++r) {
                int lrow = wm + crow + r;
                lt[lrow * 64 + lcol] = __expf(2.0f * (acc[g][r] + bv));
            }
        }
        __syncthreads();
        // h-quad gather: float4 = 4 consecutive h for one s (contiguous in lt).
        // ktT4[b][h/4][s][4]: float4-index = (b*64 + n0/4 + h4)*S + s.
        const int sbase = (int)(m0 >> 3);   // block's first s (4 total)
        const int n0q = n0 >> 2;
#pragma unroll
        for (int p = 0; p < 2; ++p) {
            int c = p * 256 + tid;
            int s_off = c & 3, h4 = (c >> 2) & 15, b2 = c >> 6;   // b2 in [0,8)
            float4 o = *(const float4*)&lt[(s_off * 8 + b2) * 64 + h4 * 4];
            size_t f4idx = ((size_t)b2 * 64 + n0q + h4) * S_DIM + sbase + s_off;
            *(float4*)&ktT[f4idx * 4] = o;
        }
    }
}

// Fused scores+softmax: block = (b, t-pair), 1024 threads (16 waves), s = tid.
// scores_row[s] = -2 * sum_h v[h]/(Eq*Ek+1), then in-block softmax over s,
// write out[b][t][s] directly.  No scores buffer, no separate softmax launch.
__global__ __launch_bounds__(1024) void scores_softmax_kernel(
    const float* __restrict__ ktT, const float* __restrict__ tq2,
    const float* __restrict__ v, float* __restrict__ out)
{
    __shared__ float redm[2][16], reds[2][16];
    const int tid = threadIdx.x, lane = tid & 63;
    const int wid = __builtin_amdgcn_readfirstlane(tid >> 6);   // 0..15
    const int bid = blockIdx.x;                   // [0,256)
    const int b = bid & 7;
    const int t0 = (bid >> 3) * 2;                // this block's 2 t-rows
    const int s = tid;                            // full row: s = 0..1023

    const float4* kb4 = (const float4*)ktT + (size_t)b * 64 * S_DIM + s;  // +h4*S per quad
    const float* q0p = tq2 + ((size_t)b * T_DIM + t0) * H_DIM;
    const float* q1p = q0p + H_DIM;

    float a0 = 0.f, a1 = 0.f;
#pragma unroll 8
    for (int h4 = 0; h4 < H_DIM / 4; ++h4) {
        float4 k4 = kb4[(size_t)h4 * S_DIM];              // coalesced 16B/lane
        float4 vv = *(const float4*)&v[h4 * 4];           // uniform dwordx4
        float4 q0 = *(const float4*)&q0p[h4 * 4];
        float4 q1 = *(const float4*)&q1p[h4 * 4];
        float A, B;
        A = fmaf(q0.x, k4.x, 1.0f); B = fmaf(q0.y, k4.y, 1.0f);
        a0 = fmaf(fmaf(vv.x, B, vv.y * A), fast_rcp(A * B), a0);
        A = fmaf(q0.z, k4.z, 1.0f); B = fmaf(q0.w, k4.w, 1.0f);
        a0 = fmaf(fmaf(vv.z, B, vv.w * A), fast_rcp(A * B), a0);
        A = fmaf(q1.x, k4.x, 1.0f); B = fmaf(q1.y, k4.y, 1.0f);
        a1 = fmaf(fmaf(vv.x, B, vv.y * A), fast_rcp(A * B), a1);
        A = fmaf(q1.z, k4.z, 1.0f); B = fmaf(q1.w, k4.w, 1.0f);
        a1 = fmaf(fmaf(vv.z, B, vv.w * A), fast_rcp(A * B), a1);
    }
    a0 *= -2.0f;
    a1 *= -2.0f;

    // ---- block softmax over s (1024 values per t-row) ----
    float m0 = a0, m1 = a1;
#pragma unroll
    for (int mm = 32; mm >= 1; mm >>= 1) {
        m0 = fmaxf(m0, __shfl_xor(m0, mm, 64));
        m1 = fmaxf(m1, __shfl_xor(m1, mm, 64));
    }
    if (lane == 0) { redm[0][wid] = m0; redm[1][wid] = m1; }
    __syncthreads();
    m0 = redm[0][0]; m1 = redm[1][0];
#pragma unroll
    for (int i = 1; i < 16; ++i) {
        m0 = fmaxf(m0, redm[0][i]);
        m1 = fmaxf(m1, redm[1][i]);
    }

    float e0 = __expf(a0 - m0), e1 = __expf(a1 - m1);
    float s0 = e0, s1 = e1;
#pragma unroll
    for (int mm = 32; mm >= 1; mm >>= 1) {
        s0 += __shfl_xor(s0, mm, 64);
        s1 += __shfl_xor(s1, mm, 64);
    }
    if (lane == 0) { reds[0][wid] = s0; reds[1][wid] = s1; }
    __syncthreads();
    s0 = 0.f; s1 = 0.f;
#pragma unroll
    for (int i = 0; i < 16; ++i) { s0 += reds[0][i]; s1 += reds[1][i]; }

    float* o = out + ((size_t)b * T_DIM + t0) * S_DIM + s;
    o[0]     = e0 * fast_rcp(s0);
    o[S_DIM] = e1 * fast_rcp(s1);
}

extern "C" void kernel_launch(void* const* d_in, const int* in_sizes, int n_in,
                              void* d_out, int out_size, void* d_ws, size_t ws_size,
                              hipStream_t stream)
{
    const float* key   = (const float*)d_in[0];
    const float* query = (const float*)d_in[1];
    const float* Wk    = (const float*)d_in[2];
    const float* bk    = (const float*)d_in[3];
    const float* Wq    = (const float*)d_in[4];
    const float* bq    = (const float*)d_in[5];
    const float* v     = (const float*)d_in[6];
    float* out = (float*)d_out;

    float* ktT    = (float*)d_ws;                       // B*(H/4)*S*4 f32 (8.39 MB) Ek h-quad
    float* tq2    = ktT + (size_t)B_DIM * H_DIM * S_DIM;// B*T*H f32  (0.52 MB)  Eq
    f16* WTk = (f16*)(tq2 + (size_t)B_DIM * T_DIM * H_DIM);     // H*K f16
    f16* WTq = WTk + (size_t)H_DIM * K_DIM;                     // H*K f16

    wconv_kernel<<<64, 256, 0, stream>>>(Wk, Wq, WTk, WTq);
    proj_gemm_all<<<1088, 256, 0, stream>>>(key, WTk, bk, ktT, query, WTq, bq, tq2);
    scores_softmax_kernel<<<256, 1024, 0, stream>>>(ktT, tq2, v, out);
}